// Round 1
// baseline (445.012 us; speedup 1.0000x reference)
//
#include <hip/hip_runtime.h>

#define W  320
#define TJ 64

typedef __attribute__((ext_vector_type(8))) short   short8;
typedef __attribute__((ext_vector_type(4))) float   floatx4;

__device__ __forceinline__ unsigned int f2bf(float f) {
    // round-to-nearest-even fp32 -> bf16 (returned in low 16 bits)
    unsigned int u = __float_as_uint(f);
    u += 0x7FFFu + ((u >> 16) & 1u);
    return u >> 16;
}

// LDS: R rows only, 128 rows x 128 shorts (256 B), no pad. Conflict-free via
// XOR swizzle of the 16-B chunk index: chunk' = chunk ^ (row & 15).
// A fragments are loaded per-wave directly from global into registers (the
// 32 KB L tile is block-local -> L1/L2 hits for the duplicated wave pair).
// 32 KB LDS => 4 blocks/CU = 32 waves/CU (wave cap), vs 3 blocks at 48 KB.
__global__ __launch_bounds__(512, 8)
void cost_volume_kernel(const float* __restrict__ Lg,
                        const float* __restrict__ Rg,
                        float* __restrict__ out) {
    __shared__ unsigned short S[128 * 128];   // 32 KB

    // XCD-chunked swizzle: 6400 blocks = 8 XCDs x 800. Consecutive work items
    // (same bh, adjacent jt -> 63 shared R rows) stay on one XCD's L2.
    const int lin  = blockIdx.x;
    const int work = (lin & 7) * 800 + (lin >> 3);
    const int bh   = work / 5;
    const int jt   = work - bh * 5;
    const int j0   = jt * TJ;
    const int tid  = threadIdx.x;

    // staging decomposition: 32 threads per row, 4 floats each
    const int lr    = tid >> 5;          // 0..15 rows per pass
    const int half  = tid & 1;           // which 8-B half of a 16-B chunk
    const int chunk = (tid & 31) >> 1;   // 0..15
    const int cf    = (tid & 31) << 2;   // float offset 0..124

    // wave decomposition for the MFMA band
    const int wave = tid >> 6;           // 0..7
    const int lane = tid & 63;
    const int col  = lane & 15;
    const int quad = lane >> 4;
    const int mt   = wave >> 1;          // 0..3
    const int g    = wave & 1;
    const int m0   = mt * 16;
    const int ntb  = mt + g * 3;         // g=0: {mt..mt+2}; g=1: {mt+3,mt+4}
    const int NT   = g ? 2 : 3;

    // ---- stage R: 128 rows (k = j0-63+rr), zero-fill OOB ----
    const float* Rrow0 = Rg + (size_t)(bh * W) * 128;
    #pragma unroll
    for (int p = 0; p < 8; ++p) {
        const int rr = p * 16 + lr;
        const int k  = j0 - 63 + rr;
        floatx4 v;
        v.x = 0.f; v.y = 0.f; v.z = 0.f; v.w = 0.f;
        if (k >= 0 && k < W) v = *(const floatx4*)(Rrow0 + (size_t)k * 128 + cf);
        uint2 d;
        d.x = f2bf(v.x) | (f2bf(v.y) << 16);
        d.y = f2bf(v.z) | (f2bf(v.w) << 16);
        const int sw = chunk ^ (rr & 15);
        *(uint2*)&S[rr * 128 + (sw << 3) + half * 4] = d;
    }

    // ---- A fragments: direct global -> regs -> bf16 (no LDS, no barrier dep)
    // A layout for 16x16x32: lane holds row = m0+col, k = ks*32 + quad*8 + 0..7
    const float* Arow = Lg + (size_t)(bh * W + j0 + m0 + col) * 128 + quad * 8;
    short8 af[4];
    #pragma unroll
    for (int ks = 0; ks < 4; ++ks) {
        floatx4 lo = *(const floatx4*)(Arow + ks * 32);
        floatx4 hi = *(const floatx4*)(Arow + ks * 32 + 4);
        short8 a;
        a[0] = (short)f2bf(lo.x); a[1] = (short)f2bf(lo.y);
        a[2] = (short)f2bf(lo.z); a[3] = (short)f2bf(lo.w);
        a[4] = (short)f2bf(hi.x); a[5] = (short)f2bf(hi.y);
        a[6] = (short)f2bf(hi.z); a[7] = (short)f2bf(hi.w);
        af[ks] = a;
    }

    __syncthreads();

    floatx4 acc[3];
    #pragma unroll
    for (int t = 0; t < 3; ++t) { acc[t].x = 0.f; acc[t].y = 0.f; acc[t].z = 0.f; acc[t].w = 0.f; }

    #pragma unroll
    for (int ks = 0; ks < 4; ++ks) {
        const int sc = (ks * 4 + quad) ^ col;   // row&15 == col on both operands
        #pragma unroll
        for (int t = 0; t < 3; ++t) {
            if (t < NT) {
                const int nrow = (ntb + t) * 16 + col;
                const short8 bf = *(const short8*)&S[nrow * 128 + (sc << 3)];
                acc[t] = __builtin_amdgcn_mfma_f32_16x16x32_bf16(af[ks], bf, acc[t], 0, 0, 0);
            }
        }
    }

    // ---- epilogue: C/D layout col=lane&15, row=quad*4+reg; i = m + 63 - n ----
    float* obase = out + (size_t)(bh * W + j0) * 64;
    #pragma unroll
    for (int t = 0; t < 3; ++t) {
        if (t < NT) {
            const int n = (ntb + t) * 16 + col;
            #pragma unroll
            for (int r = 0; r < 4; ++r) {
                const int m = m0 + quad * 4 + r;
                const int i = m + 63 - n;
                if (i >= 0 && i < 64) {
                    obase[m * 64 + i] = acc[t][r] * 0.0078125f;   // /128
                }
            }
        }
    }
}

extern "C" void kernel_launch(void* const* d_in, const int* in_sizes, int n_in,
                              void* d_out, int out_size, void* d_ws, size_t ws_size,
                              hipStream_t stream) {
    const float* L = (const float*)d_in[0];
    const float* R = (const float*)d_in[1];
    float* out = (float*)d_out;
    dim3 grid(8 * 160 * (W / TJ));   // 6400 blocks, 1-D for XCD swizzle
    cost_volume_kernel<<<grid, 512, 0, stream>>>(L, R, out);
}

// Round 2
// 431.997 us; speedup vs baseline: 1.0301x; 1.0301x over previous
//
#include <hip/hip_runtime.h>

#define W 320

typedef __attribute__((ext_vector_type(8))) short   short8;
typedef __attribute__((ext_vector_type(4))) float   floatx4;

__device__ __forceinline__ unsigned int f2bf(float f) {
    // round-to-nearest-even fp32 -> bf16 (low 16 bits)
    unsigned int u = __float_as_uint(f);
    u += 0x7FFFu + ((u >> 16) & 1u);
    return u >> 16;
}

// One block per (b,h) row. All 320 R rows staged in LDS as bf16 (80 KB),
// XOR-swizzled (chunk' = chunk ^ (row & 15)) for conflict-free ds_read_b128.
// L rows are loaded per-wave direct from global into A fragments inside the
// long compute phase (each L element read exactly once grid-wide), so HBM
// issue is continuous: stage phase streams R, compute phase streams L + out.
// 640 threads = 10 waves; each wave owns m-tiles {w, w+10} (2 each, even).
// LDS 80 KB -> 2 blocks/CU = 20 waves/CU.
__global__ __launch_bounds__(640, 5)
void cost_volume_kernel(const float* __restrict__ Lg,
                        const float* __restrict__ Rg,
                        float* __restrict__ out) {
    __shared__ unsigned short S[W * 128];   // 80 KB

    const int bh  = blockIdx.x;
    const int tid = threadIdx.x;

    // ---- stage R: 320 rows, 32 threads/row -> 20 rows/pass, 16 passes ----
    const int lr    = tid >> 5;          // 0..19
    const int half  = tid & 1;           // 8-B half of a 16-B chunk
    const int chunk = (tid & 31) >> 1;   // 0..15
    const int cf    = (tid & 31) << 2;   // float offset 0..124

    const float* Rrow0 = Rg + (size_t)bh * W * 128;
    #pragma unroll
    for (int p = 0; p < 16; ++p) {
        const int k = p * 20 + lr;
        floatx4 v = *(const floatx4*)(Rrow0 + (size_t)k * 128 + cf);
        uint2 d;
        d.x = f2bf(v.x) | (f2bf(v.y) << 16);
        d.y = f2bf(v.z) | (f2bf(v.w) << 16);
        const int sw = chunk ^ (k & 15);
        *(uint2*)&S[k * 128 + (sw << 3) + half * 4] = d;
    }

    __syncthreads();

    // ---- compute: 20 m-tiles over 10 waves, 2 per wave ----
    const int wave = tid >> 6;           // 0..9
    const int lane = tid & 63;
    const int col  = lane & 15;
    const int quad = lane >> 4;

    const float* Lrow0 = Lg + (size_t)bh * W * 128;
    float* obase = out + (size_t)bh * W * 64;

    #pragma unroll
    for (int s = 0; s < 2; ++s) {
        const int mt = wave + s * 10;    // 0..19
        const int m0 = mt * 16;

        // A fragments: lane row j = m0+col, k-elems = ks*32 + quad*8 + 0..7
        const float* Arow = Lrow0 + (size_t)(m0 + col) * 128 + quad * 8;
        short8 af[4];
        #pragma unroll
        for (int ks = 0; ks < 4; ++ks) {
            floatx4 lo = *(const floatx4*)(Arow + ks * 32);
            floatx4 hi = *(const floatx4*)(Arow + ks * 32 + 4);
            short8 a;
            a[0] = (short)f2bf(lo.x); a[1] = (short)f2bf(lo.y);
            a[2] = (short)f2bf(lo.z); a[3] = (short)f2bf(lo.w);
            a[4] = (short)f2bf(hi.x); a[5] = (short)f2bf(hi.y);
            a[6] = (short)f2bf(hi.z); a[7] = (short)f2bf(hi.w);
            af[ks] = a;
        }

        // n-window: k in [m0-64, m0+16), 5 aligned 16-tiles; negative tiles
        // skip MFMA (acc stays 0 -> stores write the required zeros).
        floatx4 acc[5];
        #pragma unroll
        for (int t = 0; t < 5; ++t) {
            acc[t].x = 0.f; acc[t].y = 0.f; acc[t].z = 0.f; acc[t].w = 0.f;
        }

        const int kbase = m0 - 64;
        #pragma unroll
        for (int t = 0; t < 5; ++t) {
            const int kt = kbase + t * 16;
            if (kt >= 0) {                       // wave-uniform branch
                const int krow = kt + col;       // krow & 15 == col
                #pragma unroll
                for (int ks = 0; ks < 4; ++ks) {
                    const int sc = (ks * 4 + quad) ^ col;
                    const short8 bf = *(const short8*)&S[krow * 128 + (sc << 3)];
                    acc[t] = __builtin_amdgcn_mfma_f32_16x16x32_bf16(af[ks], bf, acc[t], 0, 0, 0);
                }
            }
        }

        // ---- epilogue: C/D layout col=lane&15 (n), row=quad*4+r (m);
        // i = j - k = 64 + (quad*4+r) - t*16 - col
        #pragma unroll
        for (int t = 0; t < 5; ++t) {
            #pragma unroll
            for (int r = 0; r < 4; ++r) {
                const int m = quad * 4 + r;
                const int i = 64 + m - t * 16 - col;
                if (i >= 0 && i < 64) {
                    obase[(size_t)(m0 + m) * 64 + i] = acc[t][r] * 0.0078125f;  // /128
                }
            }
        }
    }
}

extern "C" void kernel_launch(void* const* d_in, const int* in_sizes, int n_in,
                              void* d_out, int out_size, void* d_ws, size_t ws_size,
                              hipStream_t stream) {
    const float* L = (const float*)d_in[0];
    const float* R = (const float*)d_in[1];
    float* out = (float*)d_out;
    dim3 grid(8 * 160);   // one block per (b,h) row
    cost_volume_kernel<<<grid, 640, 0, stream>>>(L, R, out);
}